// Round 6
// baseline (434.999 us; speedup 1.0000x reference)
//
#include <hip/hip_runtime.h>
#include <hip/hip_bf16.h>

#define M_TOKENS 4096
#define K_IN     4096
#define N_OUT    11008

#define BM 256
#define BN 256
#define BK 64
#define KTILES (K_IN / BK)   // 64

typedef __bf16 bf16x8 __attribute__((ext_vector_type(8)));
typedef float  f32x4  __attribute__((ext_vector_type(4)));

__device__ __forceinline__ void async_copy16(const void* g, void* l) {
    __builtin_amdgcn_global_load_lds(
        (const __attribute__((address_space(1))) void*)g,
        (__attribute__((address_space(3))) void*)l, 16, 0, 0);
}

// ---- x fp32 -> bf16 cast, 8 elems/thread ----
__global__ __launch_bounds__(256) void cast_x_kernel(const float* __restrict__ x,
                                                     __hip_bfloat16* __restrict__ xb) {
    size_t idx = (size_t)blockIdx.x * 256 + threadIdx.x;
    const float4* xf = reinterpret_cast<const float4*>(x) + idx * 2;
    float4 a = xf[0], b = xf[1];
    float v[8] = {a.x, a.y, a.z, a.w, b.x, b.y, b.z, b.w};
    alignas(16) __hip_bfloat16 t[8];
#pragma unroll
    for (int j = 0; j < 8; ++j) t[j] = __float2bfloat16(v[j]);
    *reinterpret_cast<uint4*>(xb + idx * 8) = *reinterpret_cast<const uint4*>(t);
}

// ---- int4-code dequant: wq[n,k] int32 -> wb[n,k] bf16 (B^T layout), 8 k/thread ----
__global__ __launch_bounds__(256) void dequant_kernel(const int* __restrict__ wq,
                                                      const float* __restrict__ snz,
                                                      __hip_bfloat16* __restrict__ wb) {
    size_t idx = (size_t)blockIdx.x * 256 + threadIdx.x;   // n*(K/8) + k8
    int n  = (int)(idx >> 9);         // K_IN/8 = 512
    int k8 = (int)(idx & 511);
    int g  = k8 >> 4;                 // (k8*8)/128
    const float* sz = snz + ((size_t)g * N_OUT + n) * 2;
    float scale = sz[0], zero = sz[1];
    const int4* q4 = reinterpret_cast<const int4*>(wq + (size_t)n * K_IN + (size_t)k8 * 8);
    int4 qa = q4[0], qb = q4[1];
    int q[8] = {qa.x, qa.y, qa.z, qa.w, qb.x, qb.y, qb.z, qb.w};
    alignas(16) __hip_bfloat16 t[8];
#pragma unroll
    for (int j = 0; j < 8; ++j)
        t[j] = __float2bfloat16((float)(q[j] - 8) * scale + zero);
    *reinterpret_cast<uint4*>(wb + idx * 8) = *reinterpret_cast<const uint4*>(t);
}

// ====== 256x256 bf16 GEMM, chunk-level software pipeline (read 1 chunk ahead) ======
// C[M,N] = Xb[M,K] @ Wb[N,K]^T, fp32 out. 8 waves (2M x 4N), BK=64.
// Rounds 2/4/5 all measured ~4913 cyc/K-tile = LDS(2304) + MFMA(2482) fully
// SERIALIZED: each wave's read-chunk -> lgkm-wait -> consume chain makes all
// waves burst reads together, wait together, MFMA together (lockstep).
// Fix: every fragment set is read ONE chunk ahead of use. Next tile's chunk-0
// reads issue during this tile's chunk-3 MFMAs, enabled by:
//   mid-tile:  s_waitcnt vmcnt(0)  + s_barrier  (next buffer staged & visible;
//              staging was issued a full tile earlier -> drain is ~free)
//   boundary:  s_waitcnt lgkmcnt(0) + s_barrier (all reads of current buffer
//              complete CU-wide before it gets re-staged next tile)
// Both are WAIT-THEN-BARRIER (round-3 invariant). No sched pins inside chunk
// regions: compiler interleaves ds_read issue with MFMA issue freely.

#define SCB()  __builtin_amdgcn_sched_barrier(0)
#define MIDSYNC() { SCB(); \
    asm volatile("s_waitcnt vmcnt(0)" ::: "memory"); \
    __builtin_amdgcn_s_barrier(); SCB(); }
#define ENDSYNC() { SCB(); \
    asm volatile("s_waitcnt lgkmcnt(0)" ::: "memory"); \
    __builtin_amdgcn_s_barrier(); SCB(); }

#define RD_A(DST, T, HALF, KK) \
    _Pragma("unroll") for (int mi = 0; mi < 4; ++mi) DST[mi] = readA(T, (HALF) * 4 + mi, KK);
#define RD_B(DST, T, KK) \
    _Pragma("unroll") for (int ni = 0; ni < 4; ++ni) DST[ni] = readB(T, ni, KK);

#define MFMA16(AOFF, AFRAG, BFRAG) \
    __builtin_amdgcn_s_setprio(1); \
    { \
        _Pragma("unroll") for (int mi = 0; mi < 4; ++mi) \
        _Pragma("unroll") for (int ni = 0; ni < 4; ++ni) \
            acc[AOFF + mi][ni] = __builtin_amdgcn_mfma_f32_16x16x32_bf16( \
                AFRAG[mi], BFRAG[ni], acc[AOFF + mi][ni], 0, 0, 0); \
    } \
    __builtin_amdgcn_s_setprio(0);

// One K-tile. Entering: aEven/bCur hold this tile's chunk-0 frags (read last tile).
// CA/CB = current buffers, NA/NB = next buffers. KN = K-tile index staged into NA/NB.
#define TILE(CA, CB, NA, NB, KN) \
    stageA(NA, KN); stageB(NB, KN); \
    /* chunk0 */ \
    RD_A(aOdd, CA, 1, 0); \
    MFMA16(0, aEven, bCur); \
    /* chunk1 */ \
    RD_A(aEven, CA, 0, 1); RD_B(bNxt, CB, 1); \
    MFMA16(4, aOdd, bCur); \
    /* chunk2 */ \
    RD_A(aOdd, CA, 1, 1); \
    MFMA16(0, aEven, bNxt); \
    MIDSYNC();   /* NA/NB contents now visible to all waves */ \
    /* chunk3 + prefetch next tile's chunk0 */ \
    RD_A(aEven, NA, 0, 0); RD_B(bCur, NB, 0); \
    MFMA16(4, aOdd, bNxt); \
    ENDSYNC();   /* all reads of CA/CB drained CU-wide; safe to re-stage */

__global__ __launch_bounds__(512, 2) void gemm8p_kernel(
        const __hip_bfloat16* __restrict__ Xb,
        const __hip_bfloat16* __restrict__ Wb,
        float* __restrict__ C) {
    __shared__ alignas(16) char smem[131072];
    char* const ldsA = smem;            // [2][256 rows][64 bf16 = 128B]
    char* const ldsB = smem + 65536;

    const int tid  = threadIdx.x;
    const int lane = tid & 63;
    const int wave = tid >> 6;
    const int wr   = wave >> 2;     // 0..1  (M half)
    const int wc   = wave & 3;      // 0..3  (N quarter)
    const int l15  = lane & 15;
    const int lrow = lane >> 3;     // staging row-in-chunk
    const int ssw  = (((lane & 7) ^ lrow) << 4);   // pre-swizzled source col (bytes)

    // XCD-bijective swizzle (grid = 688, 688 % 8 == 0)
    unsigned bid = blockIdx.x;
    unsigned per = gridDim.x >> 3;               // 86
    unsigned swz = (bid & 7u) * per + (bid >> 3);
    const int tn = (int)(swz % (N_OUT / BN));    // 43
    const int tm = (int)(swz / (N_OUT / BN));    // 16
    const int m0 = tm * BM;
    const int n0 = tn * BN;

    // swizzled read column (bytes within a 128B row); kk toggles bit 6
    const int colswz = (((lane >> 4) << 4) ^ ((lane & 7) << 4));

    f32x4 acc[8][4];
#pragma unroll
    for (int i = 0; i < 8; ++i)
#pragma unroll
        for (int j = 0; j < 4; ++j) {
            f32x4 z = {0.f, 0.f, 0.f, 0.f};
            acc[i][j] = z;
        }
    bf16x8 aEven[4], aOdd[4], bCur[4], bNxt[4];

    // stage a full 32KB tile (4 x global_load_lds/thread, 8 rows per chunk)
    auto stageA = [&](char* dstTile, int kt) {
#pragma unroll
        for (int j = 0; j < 4; ++j) {
            int rb = (wave * 4 + j) * 8;
            const char* g = (const char*)Xb + ((size_t)(m0 + rb + lrow) * K_IN) * 2
                            + (size_t)kt * 128 + ssw;
            async_copy16(g, dstTile + rb * 128);
        }
    };
    auto stageB = [&](char* dstTile, int kt) {
#pragma unroll
        for (int j = 0; j < 4; ++j) {
            int rb = (wave * 4 + j) * 8;
            const char* g = (const char*)Wb + ((size_t)(n0 + rb + lrow) * K_IN) * 2
                            + (size_t)kt * 128 + ssw;
            async_copy16(g, dstTile + rb * 128);
        }
    };
    auto readA = [&](char* tile, int mi8, int kk) -> bf16x8 {
        return *(const bf16x8*)(tile + (wr * 128 + mi8 * 16 + l15) * 128 + (colswz ^ (kk << 6)));
    };
    auto readB = [&](char* tile, int ni4, int kk) -> bf16x8 {
        return *(const bf16x8*)(tile + (wc * 64 + ni4 * 16 + l15) * 128 + (colswz ^ (kk << 6)));
    };

    char* const A0 = ldsA;   char* const A1 = ldsA + 32768;
    char* const B0 = ldsB;   char* const B1 = ldsB + 32768;

    // ---- prologue: stage tile 0 -> buf0; drain; pre-read tile0 chunk0 frags ----
    stageA(A0, 0); stageB(B0, 0);
    MIDSYNC();
    RD_A(aEven, A0, 0, 0); RD_B(bCur, B0, 0);

    for (int i = 0; i < KTILES / 2; ++i) {
        const int k1 = (2 * i + 1) & (KTILES - 1);
        const int k2 = (2 * i + 2) & (KTILES - 1);   // wraps on last iter: dead stage/reads, harmless
        TILE(A0, B0, A1, B1, k1)   // consume buf0, stage k1 -> buf1
        TILE(A1, B1, A0, B0, k2)   // consume buf1, stage k2 -> buf0
    }

    // ---- epilogue: D layout col=lane&15, row=(lane>>4)*4+e ----
    const int r4 = (lane >> 4) << 2;
#pragma unroll
    for (int mi = 0; mi < 8; ++mi)
#pragma unroll
        for (int ni = 0; ni < 4; ++ni)
#pragma unroll
            for (int e = 0; e < 4; ++e) {
                int row = m0 + wr * 128 + mi * 16 + r4 + e;
                int col = n0 + wc * 64 + ni * 16 + l15;
                C[(size_t)row * N_OUT + col] = acc[mi][ni][e];
            }
}

extern "C" void kernel_launch(void* const* d_in, const int* in_sizes, int n_in,
                              void* d_out, int out_size, void* d_ws, size_t ws_size,
                              hipStream_t stream) {
    const float* x   = (const float*)d_in[0];
    const int*   wq  = (const int*)d_in[1];
    const float* snz = (const float*)d_in[2];
    float* out = (float*)d_out;

    __hip_bfloat16* Xb = (__hip_bfloat16*)d_ws;                                        // 32 MB
    __hip_bfloat16* Wb = (__hip_bfloat16*)((char*)d_ws + (size_t)M_TOKENS * K_IN * 2); // 86 MB

    cast_x_kernel<<<(M_TOKENS * (size_t)K_IN) / 8 / 256, 256, 0, stream>>>(x, Xb);
    dequant_kernel<<<((size_t)N_OUT * K_IN) / 8 / 256, 256, 0, stream>>>(wq, snz, Wb);
    gemm8p_kernel<<<(M_TOKENS / BM) * (N_OUT / BN), 512, 0, stream>>>(Xb, Wb, out);
}

// Round 7
// 424.196 us; speedup vs baseline: 1.0255x; 1.0255x over previous
//
#include <hip/hip_runtime.h>
#include <hip/hip_bf16.h>

#define M_TOKENS 4096
#define K_IN     4096
#define N_OUT    11008

#define BM 256
#define BN 256
#define BK 64
#define KTILES (K_IN / BK)   // 64

typedef __bf16 bf16x8 __attribute__((ext_vector_type(8)));
typedef float  f32x4  __attribute__((ext_vector_type(4)));

__device__ __forceinline__ void async_copy16(const void* g, void* l) {
    __builtin_amdgcn_global_load_lds(
        (const __attribute__((address_space(1))) void*)g,
        (__attribute__((address_space(3))) void*)l, 16, 0, 0);
}

// ---- x fp32 -> bf16 cast, 8 elems/thread ----
__global__ __launch_bounds__(256) void cast_x_kernel(const float* __restrict__ x,
                                                     __hip_bfloat16* __restrict__ xb) {
    size_t idx = (size_t)blockIdx.x * 256 + threadIdx.x;
    const float4* xf = reinterpret_cast<const float4*>(x) + idx * 2;
    float4 a = xf[0], b = xf[1];
    float v[8] = {a.x, a.y, a.z, a.w, b.x, b.y, b.z, b.w};
    alignas(16) __hip_bfloat16 t[8];
#pragma unroll
    for (int j = 0; j < 8; ++j) t[j] = __float2bfloat16(v[j]);
    *reinterpret_cast<uint4*>(xb + idx * 8) = *reinterpret_cast<const uint4*>(t);
}

// ---- int4-code dequant: wq[n,k] int32 -> wb[n,k] bf16 (B^T layout), 8 k/thread ----
__global__ __launch_bounds__(256) void dequant_kernel(const int* __restrict__ wq,
                                                      const float* __restrict__ snz,
                                                      __hip_bfloat16* __restrict__ wb) {
    size_t idx = (size_t)blockIdx.x * 256 + threadIdx.x;   // n*(K/8) + k8
    int n  = (int)(idx >> 9);         // K_IN/8 = 512
    int k8 = (int)(idx & 511);
    int g  = k8 >> 4;                 // (k8*8)/128
    const float* sz = snz + ((size_t)g * N_OUT + n) * 2;
    float scale = sz[0], zero = sz[1];
    const int4* q4 = reinterpret_cast<const int4*>(wq + (size_t)n * K_IN + (size_t)k8 * 8);
    int4 qa = q4[0], qb = q4[1];
    int q[8] = {qa.x, qa.y, qa.z, qa.w, qb.x, qb.y, qb.z, qb.w};
    alignas(16) __hip_bfloat16 t[8];
#pragma unroll
    for (int j = 0; j < 8; ++j)
        t[j] = __float2bfloat16((float)(q[j] - 8) * scale + zero);
    *reinterpret_cast<uint4*>(wb + idx * 8) = *reinterpret_cast<const uint4*>(t);
}

// ====== 256x256 bf16 GEMM: phase read-ahead + disjoint register sets ======
// Root cause of the 4-round plateau (all ~4700 cyc/tile = LDS 3080 + MFMA 2060
// SERIALIZED): every schedule so far either (a) put lgkmcnt(0) between read-issue
// and consume with no read-ahead, or (b) reused fragment regs with 1-phase gap
// (WAR forces serialization). Fix:
//   - phase p issues reads for phase p+1 into regs DISJOINT from phase p's MFMA
//     operands (6 sets: aL0,aH0,aL1,aH1,b0,b1; reuse gap >= 2 phases)
//   - counted lgkmcnt(N), N = reads just issued -> only older reads must land;
//     MFMA(p) overlaps R(p+1) completion. sched_barrier(0) after each wait
//     (rule: compiler hoists reg-only MFMA past inline-asm waits otherwise).
//   - 2 barriers/tile: end-phC {vmcnt(0)+bar} makes next tile's buffers visible
//     (youngest stage ~800cyc old, L2/L3-resident -> cheap); end-phD
//     {lgkmcnt(0)+bar} = re-stage safety (round-3 wait-then-barrier invariant).
// MFMA(A)=aL0*b0 kk0, (B)=aH0*b0, (C)=aL1*b1 kk1, (D)=aH1*b1.
// R(A)={aL0,b0} issued phD(t-1); R(B)={aH0}@phA; R(C)={aL1,b1}@phB; R(D)={aH1}@phC.

#define SCB()  __builtin_amdgcn_sched_barrier(0)
#define LGKM(N) { asm volatile("s_waitcnt lgkmcnt(" #N ")" ::: "memory"); SCB(); }
#define ENDC() { SCB(); asm volatile("s_waitcnt vmcnt(0)" ::: "memory"); \
                 __builtin_amdgcn_s_barrier(); SCB(); }
#define ENDD() { SCB(); asm volatile("s_waitcnt lgkmcnt(0)" ::: "memory"); \
                 __builtin_amdgcn_s_barrier(); SCB(); }

#define RD_A4(DST, T, HALF, KK) \
    _Pragma("unroll") for (int mi = 0; mi < 4; ++mi) DST[mi] = readA(T, (HALF) * 4 + mi, KK);
#define RD_B4(DST, T, KK) \
    _Pragma("unroll") for (int ni = 0; ni < 4; ++ni) DST[ni] = readB(T, ni, KK);

#define MFMA16(AOFF, AFRAG, BFRAG) \
    __builtin_amdgcn_s_setprio(1); \
    { \
        _Pragma("unroll") for (int mi = 0; mi < 4; ++mi) \
        _Pragma("unroll") for (int ni = 0; ni < 4; ++ni) \
            acc[AOFF + mi][ni] = __builtin_amdgcn_mfma_f32_16x16x32_bf16( \
                AFRAG[mi], BFRAG[ni], acc[AOFF + mi][ni], 0, 0, 0); \
    } \
    __builtin_amdgcn_s_setprio(0);

// One K-tile. Entering: aL0/b0 hold this tile's kk0-low frags (read in prev phD),
// already drained. CA/CB = current buffers; NA/NB = next buffers; KN staged into NA/NB.
#define TILE(CA, CB, NA, NB, KN) \
    /* phA: issue R(B); stage A(next); MFMA(A) — no wait needed */ \
    RD_A4(aH0, CA, 1, 0); \
    stageA(NA, KN); \
    MFMA16(0, aL0, b0); \
    /* phB: issue R(C); stage B(next); wait older (R(B)); MFMA(B) */ \
    RD_A4(aL1, CA, 0, 1); RD_B4(b1, CB, 1); \
    stageB(NB, KN); \
    LGKM(8); \
    MFMA16(4, aH0, b0); \
    /* phC: issue R(D); wait older (R(C)); MFMA(C); then make NA/NB visible */ \
    RD_A4(aH1, CA, 1, 1); \
    LGKM(4); \
    MFMA16(0, aL1, b1); \
    ENDC(); \
    /* phD: issue R(A,next) from NA/NB; wait older (R(D)); MFMA(D); drain+bar */ \
    RD_A4(aL0, NA, 0, 0); RD_B4(b0, NB, 0); \
    LGKM(8); \
    MFMA16(4, aH1, b1); \
    ENDD();

__global__ __launch_bounds__(512, 2) void gemm8p_kernel(
        const __hip_bfloat16* __restrict__ Xb,
        const __hip_bfloat16* __restrict__ Wb,
        float* __restrict__ C) {
    __shared__ alignas(16) char smem[131072];
    char* const ldsA = smem;            // [2][256 rows][64 bf16 = 128B]
    char* const ldsB = smem + 65536;

    const int tid  = threadIdx.x;
    const int lane = tid & 63;
    const int wave = tid >> 6;
    const int wr   = wave >> 2;     // 0..1  (M half)
    const int wc   = wave & 3;      // 0..3  (N quarter)
    const int l15  = lane & 15;
    const int lrow = lane >> 3;     // staging row-in-chunk
    const int ssw  = (((lane & 7) ^ lrow) << 4);   // pre-swizzled source col (bytes)

    // XCD-bijective swizzle (grid = 688, 688 % 8 == 0)
    unsigned bid = blockIdx.x;
    unsigned per = gridDim.x >> 3;               // 86
    unsigned swz = (bid & 7u) * per + (bid >> 3);
    const int tn = (int)(swz % (N_OUT / BN));    // 43
    const int tm = (int)(swz / (N_OUT / BN));    // 16
    const int m0 = tm * BM;
    const int n0 = tn * BN;

    // swizzled read column (bytes within a 128B row); kk toggles bit 6
    const int colswz = (((lane >> 4) << 4) ^ ((lane & 7) << 4));

    f32x4 acc[8][4];
#pragma unroll
    for (int i = 0; i < 8; ++i)
#pragma unroll
        for (int j = 0; j < 4; ++j) {
            f32x4 z = {0.f, 0.f, 0.f, 0.f};
            acc[i][j] = z;
        }
    bf16x8 aL0[4], aH0[4], aL1[4], aH1[4], b0[4], b1[4];

    // stage a full 32KB tile (4 x global_load_lds/thread, 8 rows per chunk)
    auto stageA = [&](char* dstTile, int kt) {
#pragma unroll
        for (int j = 0; j < 4; ++j) {
            int rb = (wave * 4 + j) * 8;
            const char* g = (const char*)Xb + ((size_t)(m0 + rb + lrow) * K_IN) * 2
                            + (size_t)kt * 128 + ssw;
            async_copy16(g, dstTile + rb * 128);
        }
    };
    auto stageB = [&](char* dstTile, int kt) {
#pragma unroll
        for (int j = 0; j < 4; ++j) {
            int rb = (wave * 4 + j) * 8;
            const char* g = (const char*)Wb + ((size_t)(n0 + rb + lrow) * K_IN) * 2
                            + (size_t)kt * 128 + ssw;
            async_copy16(g, dstTile + rb * 128);
        }
    };
    auto readA = [&](char* tile, int mi8, int kk) -> bf16x8 {
        return *(const bf16x8*)(tile + (wr * 128 + mi8 * 16 + l15) * 128 + (colswz ^ (kk << 6)));
    };
    auto readB = [&](char* tile, int ni4, int kk) -> bf16x8 {
        return *(const bf16x8*)(tile + (wc * 64 + ni4 * 16 + l15) * 128 + (colswz ^ (kk << 6)));
    };

    char* const A0 = ldsA;   char* const A1 = ldsA + 32768;
    char* const B0 = ldsB;   char* const B1 = ldsB + 32768;

    // ---- prologue: stage tile0 -> buf0; drain; read tile0 phA frags; drain reads ----
    stageA(A0, 0); stageB(B0, 0);
    ENDC();                       // vmcnt(0) + barrier: buf0 visible
    RD_A4(aL0, A0, 0, 0); RD_B4(b0, B0, 0);
    LGKM(0);

    for (int i = 0; i < KTILES / 2; ++i) {
        const int k1 = (2 * i + 1) & (KTILES - 1);
        const int k2 = (2 * i + 2) & (KTILES - 1);   // wraps on last iter: dead ops, harmless
        TILE(A0, B0, A1, B1, k1)   // consume buf0, stage k1 -> buf1
        TILE(A1, B1, A0, B0, k2)   // consume buf1, stage k2 -> buf0
    }

    // ---- epilogue: D layout col=lane&15, row=(lane>>4)*4+e ----
    const int r4 = (lane >> 4) << 2;
#pragma unroll
    for (int mi = 0; mi < 8; ++mi)
#pragma unroll
        for (int ni = 0; ni < 4; ++ni)
#pragma unroll
            for (int e = 0; e < 4; ++e) {
                int row = m0 + wr * 128 + mi * 16 + r4 + e;
                int col = n0 + wc * 64 + ni * 16 + l15;
                C[(size_t)row * N_OUT + col] = acc[mi][ni][e];
            }
}

extern "C" void kernel_launch(void* const* d_in, const int* in_sizes, int n_in,
                              void* d_out, int out_size, void* d_ws, size_t ws_size,
                              hipStream_t stream) {
    const float* x   = (const float*)d_in[0];
    const int*   wq  = (const int*)d_in[1];
    const float* snz = (const float*)d_in[2];
    float* out = (float*)d_out;

    __hip_bfloat16* Xb = (__hip_bfloat16*)d_ws;                                        // 32 MB
    __hip_bfloat16* Wb = (__hip_bfloat16*)((char*)d_ws + (size_t)M_TOKENS * K_IN * 2); // 86 MB

    cast_x_kernel<<<(M_TOKENS * (size_t)K_IN) / 8 / 256, 256, 0, stream>>>(x, Xb);
    dequant_kernel<<<((size_t)N_OUT * K_IN) / 8 / 256, 256, 0, stream>>>(wq, snz, Wb);
    gemm8p_kernel<<<(M_TOKENS / BM) * (N_OUT / BN), 512, 0, stream>>>(Xb, Wb, out);
}

// Round 8
// 389.538 us; speedup vs baseline: 1.1167x; 1.0890x over previous
//
#include <hip/hip_runtime.h>
#include <hip/hip_bf16.h>

#define M_TOKENS 4096
#define K_IN     4096
#define N_OUT    11008

#define BM 256
#define BN 256
#define BK 64
#define KTILES (K_IN / BK)   // 64

typedef __bf16 bf16x8 __attribute__((ext_vector_type(8)));
typedef float  f32x4  __attribute__((ext_vector_type(4)));

__device__ __forceinline__ void async_copy16(const void* g, void* l) {
    __builtin_amdgcn_global_load_lds(
        (const __attribute__((address_space(1))) void*)g,
        (__attribute__((address_space(3))) void*)l, 16, 0, 0);
}

// ---- x fp32 -> bf16 cast, 8 elems/thread ----
__global__ __launch_bounds__(256) void cast_x_kernel(const float* __restrict__ x,
                                                     __hip_bfloat16* __restrict__ xb) {
    size_t idx = (size_t)blockIdx.x * 256 + threadIdx.x;
    const float4* xf = reinterpret_cast<const float4*>(x) + idx * 2;
    float4 a = xf[0], b = xf[1];
    float v[8] = {a.x, a.y, a.z, a.w, b.x, b.y, b.z, b.w};
    alignas(16) __hip_bfloat16 t[8];
#pragma unroll
    for (int j = 0; j < 8; ++j) t[j] = __float2bfloat16(v[j]);
    *reinterpret_cast<uint4*>(xb + idx * 8) = *reinterpret_cast<const uint4*>(t);
}

// ---- int4-code dequant: wq[n,k] int32 -> wb[n,k] bf16 (B^T layout), 8 k/thread ----
__global__ __launch_bounds__(256) void dequant_kernel(const int* __restrict__ wq,
                                                      const float* __restrict__ snz,
                                                      __hip_bfloat16* __restrict__ wb) {
    size_t idx = (size_t)blockIdx.x * 256 + threadIdx.x;   // n*(K/8) + k8
    int n  = (int)(idx >> 9);         // K_IN/8 = 512
    int k8 = (int)(idx & 511);
    int g  = k8 >> 4;                 // (k8*8)/128
    const float* sz = snz + ((size_t)g * N_OUT + n) * 2;
    float scale = sz[0], zero = sz[1];
    const int4* q4 = reinterpret_cast<const int4*>(wq + (size_t)n * K_IN + (size_t)k8 * 8);
    int4 qa = q4[0], qb = q4[1];
    int q[8] = {qa.x, qa.y, qa.z, qa.w, qb.x, qb.y, qb.z, qb.w};
    alignas(16) __hip_bfloat16 t[8];
#pragma unroll
    for (int j = 0; j < 8; ++j)
        t[j] = __float2bfloat16((float)(q[j] - 8) * scale + zero);
    *reinterpret_cast<uint4*>(wb + idx * 8) = *reinterpret_cast<const uint4*>(t);
}

// ====== 256x256 bf16 GEMM — faithful m201 8-phase template ======
// Per phase: {reads; 1 stage unit; [lgkm8 if 12 reads]; s_barrier; lgkmcnt(0);
// setprio(1); 16 MFMA; setprio(0); s_barrier}. NO sched_barriers (reads are
// compiler-visible; m141: sched_barrier pins cost -42%). Overlap mechanism:
// per-wave lgkmcnt(0) -> waves start MFMA staggered by DS-FIFO position, so
// early waves' MFMAs overlap late waves' LDS service within each phase.
// Read split per K-tile (quadrants): phA: aL(kk0+1)+b[0:1](kk0+1) = 12 reads,
// 16 MFMA aL*b01; phB: b[2:3] = 4, aL*b23; phC: aH = 8, aH*b01; phD: 0, aH*b23.
// Stage cadence (1 unit = 2 gload_lds/thread; ledger-verified, 3 units in
// flight at the wait): phA: B(t+1)u1; phB: A(t+1)u1; phC: A(t+2)u0 (into CA:
// A-u0 reads drained by phA's lgkm0, 2 barriers earlier); phD: B(t+2)u0 (into
// CB: b reads drained by phB). vmcnt(4) once/tile before closing barrier
// (wait-then-barrier, round-3 invariant); youngest required unit ~2 phases old.
// Units match read-phase rows exactly: A-u0 = aL rows {0-63,128-191},
// B-u0 = b[0:1] rows {0-31,64-95,128-159,192-223}.

#define LGKM8() asm volatile("s_waitcnt lgkmcnt(8)" ::: "memory")
#define LGKM0() asm volatile("s_waitcnt lgkmcnt(0)" ::: "memory")
#define VM4()   asm volatile("s_waitcnt vmcnt(4)" ::: "memory")
#define BAR()   __builtin_amdgcn_s_barrier()

#define RD_AL2(T) \
    _Pragma("unroll") for (int mi = 0; mi < 4; ++mi) \
    _Pragma("unroll") for (int kk = 0; kk < 2; ++kk) aL[mi][kk] = readA(T, mi, kk);
#define RD_AH2(T) \
    _Pragma("unroll") for (int mi = 0; mi < 4; ++mi) \
    _Pragma("unroll") for (int kk = 0; kk < 2; ++kk) aH[mi][kk] = readA(T, 4 + mi, kk);
#define RD_B2(T, H) \
    _Pragma("unroll") for (int ni = 0; ni < 2; ++ni) \
    _Pragma("unroll") for (int kk = 0; kk < 2; ++kk) bfr[(H) * 2 + ni][kk] = readB(T, (H) * 2 + ni, kk);

#define MFMA8x2(AOFF, FRAG, NIBASE) \
    __builtin_amdgcn_s_setprio(1); \
    { \
        _Pragma("unroll") for (int kk = 0; kk < 2; ++kk) \
        _Pragma("unroll") for (int mi = 0; mi < 4; ++mi) \
        _Pragma("unroll") for (int ni = 0; ni < 2; ++ni) \
            acc[AOFF + mi][NIBASE + ni] = __builtin_amdgcn_mfma_f32_16x16x32_bf16( \
                FRAG[mi][kk], bfr[NIBASE + ni][kk], acc[AOFF + mi][NIBASE + ni], 0, 0, 0); \
    } \
    __builtin_amdgcn_s_setprio(0);

// One K-tile t: consume (CA,CB); K1 = t+1 units into (NA,NB); K2 = t+2 units into (CA,CB).
#define TILE(CA, CB, NA, NB, K1, K2) \
    /* phA */ \
    RD_AL2(CA); RD_B2(CB, 0); \
    stageB(NB, K1, 1); \
    LGKM8(); BAR(); LGKM0(); \
    MFMA8x2(0, aL, 0); \
    BAR(); \
    /* phB */ \
    RD_B2(CB, 1); \
    stageA(NA, K1, 1); \
    BAR(); LGKM0(); \
    MFMA8x2(0, aL, 2); \
    BAR(); \
    /* phC */ \
    RD_AH2(CA); \
    stageA(CA, K2, 0); \
    BAR(); LGKM0(); \
    MFMA8x2(4, aH, 0); \
    BAR(); \
    /* phD */ \
    stageB(CB, K2, 0); \
    BAR(); \
    MFMA8x2(4, aH, 2); \
    VM4(); BAR();

__global__ __launch_bounds__(512, 2) void gemm8p_kernel(
        const __hip_bfloat16* __restrict__ Xb,
        const __hip_bfloat16* __restrict__ Wb,
        float* __restrict__ C) {
    __shared__ alignas(16) char smem[131072];
    char* const ldsA = smem;            // [2][256 rows][64 bf16 = 128B]
    char* const ldsB = smem + 65536;

    const int tid  = threadIdx.x;
    const int lane = tid & 63;
    const int wave = tid >> 6;
    const int wr   = wave >> 2;     // 0..1  (M half)
    const int wc   = wave & 3;      // 0..3  (N quarter)
    const int l15  = lane & 15;
    const int lrow = lane >> 3;     // staging row-in-chunk
    const int ssw  = (((lane & 7) ^ lrow) << 4);   // pre-swizzled source col (bytes)

    // XCD-bijective swizzle (grid = 688, 688 % 8 == 0)
    unsigned bid = blockIdx.x;
    unsigned per = gridDim.x >> 3;               // 86
    unsigned swz = (bid & 7u) * per + (bid >> 3);
    const int tn = (int)(swz % (N_OUT / BN));    // 43
    const int tm = (int)(swz / (N_OUT / BN));    // 16
    const int m0 = tm * BM;
    const int n0 = tn * BN;

    // swizzled read column (bytes within a 128B row); kk toggles bit 6
    const int colswz = (((lane >> 4) << 4) ^ ((lane & 7) << 4));

    f32x4 acc[8][4];
#pragma unroll
    for (int i = 0; i < 8; ++i)
#pragma unroll
        for (int j = 0; j < 4; ++j) {
            f32x4 z = {0.f, 0.f, 0.f, 0.f};
            acc[i][j] = z;
        }
    bf16x8 aL[4][2], aH[4][2], bfr[4][2];

    // stage one 16KB unit (2 x global_load_lds/thread)
    auto stageA = [&](char* dstTile, int kt, int unit) {
#pragma unroll
        for (int j = 0; j < 2; ++j) {
            int c  = wave * 2 + j;
            int rb = (c >> 3) * 128 + (c & 7) * 8 + unit * 64;   // u0: rows 0-63,128-191
            const char* g = (const char*)Xb + ((size_t)(m0 + rb + lrow) * K_IN) * 2
                            + (size_t)kt * 128 + ssw;
            async_copy16(g, dstTile + rb * 128);
        }
    };
    auto stageB = [&](char* dstTile, int kt, int unit) {
#pragma unroll
        for (int j = 0; j < 2; ++j) {
            int c  = wave * 2 + j;
            int rb = (c >> 2) * 64 + (c & 3) * 8 + unit * 32;    // u0: rows 0-31 per 64-seg
            const char* g = (const char*)Wb + ((size_t)(n0 + rb + lrow) * K_IN) * 2
                            + (size_t)kt * 128 + ssw;
            async_copy16(g, dstTile + rb * 128);
        }
    };
    auto readA = [&](char* tile, int mi8, int kk) -> bf16x8 {
        return *(const bf16x8*)(tile + (wr * 128 + mi8 * 16 + l15) * 128 + (colswz ^ (kk << 6)));
    };
    auto readB = [&](char* tile, int ni4, int kk) -> bf16x8 {
        return *(const bf16x8*)(tile + (wc * 64 + ni4 * 16 + l15) * 128 + (colswz ^ (kk << 6)));
    };

    char* const A0 = ldsA;   char* const A1 = ldsA + 32768;
    char* const B0 = ldsB;   char* const B1 = ldsB + 32768;

    // ---- prologue: tile0 full (4 units) + tile1 u0 pair; vmcnt(4): tile0 landed,
    //      {A1u0,B1u0} in flight ----
    stageA(A0, 0, 0); stageA(A0, 0, 1); stageB(B0, 0, 0); stageB(B0, 0, 1);
    stageA(A1, 1, 0); stageB(B1, 1, 0);
    VM4(); BAR();

    for (int i = 0; i < KTILES / 2; ++i) {
        const int k1 = (2 * i + 1) & (KTILES - 1);
        const int k2 = (2 * i + 2) & (KTILES - 1);
        const int k3 = (2 * i + 3) & (KTILES - 1);   // wraps on last iters: dead-but-safe stages
        TILE(A0, B0, A1, B1, k1, k2)   // tile 2i   (buf0)
        TILE(A1, B1, A0, B0, k2, k3)   // tile 2i+1 (buf1)
    }

    // ---- epilogue: D layout col=lane&15, row=(lane>>4)*4+e ----
    const int r4 = (lane >> 4) << 2;
#pragma unroll
    for (int mi = 0; mi < 8; ++mi)
#pragma unroll
        for (int ni = 0; ni < 4; ++ni)
#pragma unroll
            for (int e = 0; e < 4; ++e) {
                int row = m0 + wr * 128 + mi * 16 + r4 + e;
                int col = n0 + wc * 64 + ni * 16 + l15;
                C[(size_t)row * N_OUT + col] = acc[mi][ni][e];
            }
}

extern "C" void kernel_launch(void* const* d_in, const int* in_sizes, int n_in,
                              void* d_out, int out_size, void* d_ws, size_t ws_size,
                              hipStream_t stream) {
    const float* x   = (const float*)d_in[0];
    const int*   wq  = (const int*)d_in[1];
    const float* snz = (const float*)d_in[2];
    float* out = (float*)d_out;

    __hip_bfloat16* Xb = (__hip_bfloat16*)d_ws;                                        // 32 MB
    __hip_bfloat16* Wb = (__hip_bfloat16*)((char*)d_ws + (size_t)M_TOKENS * K_IN * 2); // 86 MB

    cast_x_kernel<<<(M_TOKENS * (size_t)K_IN) / 8 / 256, 256, 0, stream>>>(x, Xb);
    dequant_kernel<<<((size_t)N_OUT * K_IN) / 8 / 256, 256, 0, stream>>>(wq, snz, Wb);
    gemm8p_kernel<<<(M_TOKENS / BM) * (N_OUT / BN), 512, 0, stream>>>(Xb, Wb, out);
}